// Round 10
// baseline (134.401 us; speedup 1.0000x reference)
//
#include <hip/hip_runtime.h>

#define H 512
#define W 512
#define RH 508
#define RW 508
#define OH 510
#define OW 510

// Wave-autonomous rolling-row morphology. No LDS, no __syncthreads.
// Each wave owns 8 output rows x 512 cols of one (b,g). dil/ero kept in a
// 3-row rolling REGISTER window; col halo via 10-col per-lane compute
// (1.25x redundancy, no shuffles). Stores are never drained by barriers
// (R8: per-iter vmcnt(0) drain + 64% VALUBusy was the limiter).

__global__ __launch_bounds__(256) void morph2d_wave(
    const float* __restrict__ x,      // (4,512,512)
    const float* __restrict__ wgt,    // (16,3,3) binary
    float* __restrict__ out)          // (4,64,510,510)
{
    const int tid   = threadIdx.x;
    const int lane  = tid & 63;
    const int wv    = tid >> 6;                 // wave 0..3
    const int bg    = blockIdx.x & 63;          // b*16+g
    const int chunk = blockIdx.x >> 6;          // 0..15
    const int b = bg >> 4, g = bg & 15;
    const int r0 = chunk * 32 + wv * 8;         // wave's first output row (<=504)
    const int c0 = lane * 8;                    // own cols c0..c0+7

    int wm = 0;
#pragma unroll
    for (int t = 0; t < 9; ++t) wm |= (wgt[g * 9 + t] > 0.5f) ? (1 << t) : 0;
    wm = __builtin_amdgcn_readfirstlane(wm);

    const float* xb    = x + (size_t)b * (H * W);
    const size_t plane = (size_t)OH * OW;
    float*       outbg = out + (size_t)bg * 4 * plane;

    float xr[3][12];                // x rows, rolling (row m -> slot m%3)
    float dR[3][10], eR[3][10];     // dil/ero rows, rolling (row m -> slot m%3)

    auto load_xrow = [&](int rr, float (&v)[12]) {
        const float* p = xb + (size_t)rr * W + c0;
        *(float4*)&v[0] = *(const float4*)(p);
        *(float4*)&v[4] = *(const float4*)(p + 4);
        if (lane < 63) {
            *(float4*)&v[8] = *(const float4*)(p + 8);
        } else {
            v[8] = 0.f; v[9] = 0.f; v[10] = 0.f; v[11] = 0.f;
        }
    };

    auto de_tap_row = [&](const float (&xw)[12], int base, float (&d)[10], float (&e)[10]) {
#pragma unroll
        for (int tj = 0; tj < 3; ++tj) {
            if (wm & (1 << (base + tj))) {
#pragma unroll
                for (int c = 0; c < 10; ++c) {
                    float xv = xw[c + tj];
                    d[c] = fmaxf(d[c], fabsf(xv));          // |x*1|
                    e[c] = fminf(e[c], fabsf(xv + 1.0f));   // |x+1|
                }
            } else {
#pragma unroll
                for (int c = 0; c < 10; ++c)
                    e[c] = fminf(e[c], fabsf(xw[c + tj]));  // |x+0|
            }
        }
    };

    auto compute_de = [&](const float (&x0)[12], const float (&x1)[12], const float (&x2)[12],
                          float (&d)[10], float (&e)[10]) {
#pragma unroll
        for (int c = 0; c < 10; ++c) { d[c] = 0.f; e[c] = INFINITY; }
        de_tap_row(x0, 0, d, e);
        de_tap_row(x1, 3, d, e);
        de_tap_row(x2, 6, d, e);
        if (lane == 63) {                       // global de cols >= 508 are pad zeros
#pragma unroll
            for (int c = 4; c < 10; ++c) { d[c] = 0.f; e[c] = 0.f; }
        }
    };

    auto zero_de = [&](float (&d)[10], float (&e)[10]) {
#pragma unroll
        for (int c = 0; c < 10; ++c) { d[c] = 0.f; e[c] = 0.f; }
    };

    auto oc_tap_row = [&](const float (&D)[10], const float (&E)[10], int base,
                          float (&oo)[8], float (&m1)[8], float (&m0)[8]) {
#pragma unroll
        for (int tj = 0; tj < 3; ++tj) {
            if (wm & (1 << (base + tj))) {
#pragma unroll
                for (int c = 0; c < 8; ++c) {
                    oo[c] = fmaxf(oo[c], E[c + tj]);   // ero>=0: |ero*1|=ero
                    m1[c] = fminf(m1[c], D[c + tj]);   // min dil over w=1
                }
            } else {
#pragma unroll
                for (int c = 0; c < 8; ++c)
                    m0[c] = fminf(m0[c], D[c + tj]);   // min dil over w=0
            }
        }
    };

    auto store_ch = [&](int ch, int row, const float* v) {
        float* p = outbg + (size_t)ch * plane + (size_t)row * OW + c0;
        if (lane < 63) {
            __builtin_memcpy(p,     &v[0], 16);
            __builtin_memcpy(p + 4, &v[4], 16);
        } else {                                 // cols 504..509 only
            __builtin_memcpy(p,     &v[0], 16);
            __builtin_memcpy(p + 4, &v[4], 8);
        }
    };

    // ---- prologue: de rows r0, r0+1 (always < 508 since r0 <= 504) ----
    load_xrow(r0,     xr[0]);
    load_xrow(r0 + 1, xr[1]);
    load_xrow(r0 + 2, xr[2]);
    compute_de(xr[0], xr[1], xr[2], dR[0], eR[0]);
    load_xrow(r0 + 3, xr[0]);
    compute_de(xr[1], xr[2], xr[0], dR[1], eR[1]);

#pragma unroll
    for (int k = 0; k < 8; ++k) {
        const int r   = r0 + k;
        const int deR = r + 2;

        // fill slot (k+2)%3 with de row deR
        if (deR < RH) {
            load_xrow(deR + 2, xr[(k + 4) % 3]);   // x row deR+2 <= 509
            compute_de(xr[(k + 2) % 3], xr[(k + 3) % 3], xr[(k + 4) % 3],
                       dR[(k + 2) % 3], eR[(k + 2) % 3]);
        } else {
            zero_de(dR[(k + 2) % 3], eR[(k + 2) % 3]);
        }

        if (r < RH) {
            float oo[8], m1[8], m0[8], cc[8];
#pragma unroll
            for (int c = 0; c < 8; ++c) { oo[c] = 0.f; m1[c] = INFINITY; m0[c] = INFINITY; }
            oc_tap_row(dR[k % 3],       eR[k % 3],       0, oo, m1, m0);
            oc_tap_row(dR[(k + 1) % 3], eR[(k + 1) % 3], 3, oo, m1, m0);
            oc_tap_row(dR[(k + 2) % 3], eR[(k + 2) % 3], 6, oo, m1, m0);
#pragma unroll
            for (int c = 0; c < 8; ++c) cc[c] = fminf(m1[c] + 1.0f, m0[c]);
            if (lane == 63) {                      // output cols 508,509 are pad zeros
                oo[4] = 0.f; oo[5] = 0.f; cc[4] = 0.f; cc[5] = 0.f;
            }
            store_ch(0, r, dR[k % 3]);
            store_ch(1, r, eR[k % 3]);
            store_ch(2, r, oo);
            store_ch(3, r, cc);
        } else if (r < OH) {                       // rows 508,509: pad zeros
            float z[8] = {0, 0, 0, 0, 0, 0, 0, 0};
            store_ch(0, r, z); store_ch(1, r, z); store_ch(2, r, z); store_ch(3, r, z);
        }
        // r >= OH (510,511): nothing
    }
}

extern "C" void kernel_launch(void* const* d_in, const int* in_sizes, int n_in,
                              void* d_out, int out_size, void* d_ws, size_t ws_size,
                              hipStream_t stream) {
    const float* x = (const float*)d_in[0];   // (4,1,512,512) f32
    const float* w = (const float*)d_in[1];   // (16,1,3,3)  f32
    float* out = (float*)d_out;               // (4,64,510,510) f32
    dim3 grid(64 * 16);                       // (bg, chunk): 1024 blocks x 256 thr
    morph2d_wave<<<grid, 256, 0, stream>>>(x, w, out);
}